// Round 4
// baseline (7416.850 us; speedup 1.0000x reference)
//
#include <hip/hip_runtime.h>

namespace {

constexpr int T_STEPS = 32;
constexpr int BATCH   = 8192;
constexpr int H1      = 480;
constexpr int HID     = 200;
constexpr int H2      = 320;
constexpr int BR      = 16;    // rows per block = one MFMA M-tile
constexpr int NTHR    = 256;   // 4 waves

constexpr int NCHUNK = 13;     // 16-col chunks per gate (200 -> 208)
constexpr int SL_X   = 15;     // K-slices of 32 for a1 (480)
constexpr int SL_H   = 7;      // K-slices for h (200 -> 224)
constexpr int FR_WG  = NCHUNK * 3 * SL_X;  // 585 B-frags
constexpr int FR_UG  = NCHUNK * 3 * SL_H;  // 273
constexpr int FR_W2  = (H2 / 16) * SL_H;   // 140
constexpr int FRAGS  = FR_WG + FR_UG + FR_W2;  // 998
constexpr size_t WS_NEED = (size_t)FRAGS * 512 * 2;

typedef short  short8 __attribute__((ext_vector_type(8)));
typedef float  f32x4  __attribute__((ext_vector_type(4)));

__device__ __forceinline__ unsigned short f2bf(float x) {
    unsigned u = __float_as_uint(x);
    u = (u + 0x7fffu + ((u >> 16) & 1u)) >> 16;
    return (unsigned short)u;
}
__device__ __forceinline__ float bfu2f(unsigned short b) {
    return __uint_as_float(((unsigned)b) << 16);
}
__device__ __forceinline__ float sigmoid_(float x) { return 1.f / (1.f + __expf(-x)); }
__device__ __forceinline__ float tanh_(float x) {
    x = fminf(fmaxf(x, -15.f), 15.f);
    const float e = __expf(-2.f * x);
    return (1.f - e) / (1.f + e);
}
__device__ __forceinline__ f32x4 MFMA(short8 a, short8 b, f32x4 c) {
    return __builtin_amdgcn_mfma_f32_16x16x32_bf16(a, b, c, 0, 0, 0);
}
// A/B fragment element offset for (m-or-n = lane&15, k): slice-linear layout
__device__ __forceinline__ int frag_off(int k, int m) {
    return ((k >> 5) * 64 + ((k & 31) >> 3) * 16 + m) * 8 + (k & 7);
}

// ---- prep: rearrange Wg/Ug/W2 into bf16 B-fragment-linear layout in d_ws ----
// WgF: [chunk 13][gate 3][slice 15][512]; UgF: [13][3][7][512]; W2F: [tile 20][7][512]
__global__ void cvt_kernel(const float* __restrict__ Wg, const float* __restrict__ Ug,
                           const float* __restrict__ W2, unsigned short* __restrict__ o) {
    const int i = blockIdx.x * 256 + threadIdx.x;
    if (i >= FRAGS * 512) return;
    const int f = i >> 9, e = i & 511;
    const int l = e >> 3, j = e & 7;
    const int nn = l & 15, q = l >> 4;
    float v = 0.f;
    if (f < FR_WG) {
        const int c = f / 45, r = f % 45, g = r / 15, s = r % 15;
        const int n = 16 * c + nn, k = 32 * s + q * 8 + j;
        if (n < 200) v = Wg[k * 600 + g * 200 + n];
    } else if (f < FR_WG + FR_UG) {
        const int f2 = f - FR_WG, c = f2 / 21, r = f2 % 21, g = r / 7, s = r % 7;
        const int n = 16 * c + nn, k = 32 * s + q * 8 + j;
        if (n < 200 && k < 200) v = Ug[k * 600 + g * 200 + n];
    } else {
        const int f3 = f - FR_WG - FR_UG, t = f3 / 7, s = f3 % 7;
        const int n = 16 * t + nn, k = 32 * s + q * 8 + j;
        if (k < 200) v = W2[k * 320 + n];
    }
    o[i] = f2bf(v);
}

__global__ __launch_bounds__(NTHR, 3) void knet_mfma(
    const float* __restrict__ y,    // [T,B,2]
    const float* __restrict__ Fm,   // [4,4]
    const float* __restrict__ Hm,   // [2,4]
    const float* __restrict__ W1,   // [8,480]
    const float* __restrict__ b1,   // [480]
    const float* __restrict__ bg,   // [2,600]
    const float* __restrict__ b2,   // [320]
    const float* __restrict__ W3,   // [320,8]
    const float* __restrict__ b3,   // [8]
    const float* __restrict__ hn0,  // [B,200]
    const unsigned short* __restrict__ WF,  // rearranged frags
    float* __restrict__ out)        // [T,B,4]
{
    // a1 A-frags (hi|lo), unioned with a2 fp32 [320][16] (20480 B <= 30720 B)
    __shared__ __align__(16) unsigned short s_a1f[2 * SL_X * 512];  // 30720 B
    __shared__ __align__(16) unsigned short s_hf[2 * SL_H * 512];   // 14336 B
    __shared__ float s_bz[208], s_br[208], s_bhx[208], s_bhh[208];
    __shared__ float s_in8[16][9];
    __shared__ float s_dm1y[16][2], s_prior[16][4], s_post[16][4], s_kg[16][8];

    const int tid  = threadIdx.x;
    const int lane = tid & 63, wv = tid >> 6;
    const int row0 = blockIdx.x * BR;

    unsigned short* a1h = s_a1f;
    unsigned short* a1l = s_a1f + SL_X * 512;
    unsigned short* hh_ = s_hf;
    unsigned short* hl_ = s_hf + SL_H * 512;
    float* s_a2 = (float*)s_a1f;  // union

    const unsigned short* UgF = WF + (size_t)FR_WG * 512;
    const unsigned short* W2F = WF + (size_t)(FR_WG + FR_UG) * 512;

    // ---- init ----
    for (int t = tid; t < 208; t += NTHR) {
        const bool v = t < 200;
        s_bz[t]  = v ? bg[t] + bg[600 + t] : 0.f;
        s_br[t]  = v ? bg[200 + t] + bg[800 + t] : 0.f;
        s_bhx[t] = v ? bg[400 + t] : 0.f;
        s_bhh[t] = v ? bg[1000 + t] : 0.f;
    }
    for (int i = tid; i < 224 * 16; i += NTHR) {  // h0 -> hi/lo frags (+zero pad)
        const int k = i >> 4, m = i & 15;
        const float hv = (k < 200) ? hn0[(size_t)(row0 + m) * HID + k] : 0.f;
        const unsigned short hb = f2bf(hv);
        const unsigned short lb = f2bf(hv - bfu2f(hb));
        const int off = frag_off(k, m);
        hh_[off] = hb;
        hl_[off] = lb;
    }
    if (tid < 64) {
        s_prior[tid >> 2][tid & 3] = 0.f;
        s_post[tid >> 2][tid & 3]  = 0.f;
    }
    __syncthreads();

    for (int t = 0; t < T_STEPS; ++t) {
        // ---- Phase A: prior / innovation / features (16 threads) ----
        if (tid < 16) {
            const int r = tid;
            float post[4], prevpri[4], pri[4];
#pragma unroll
            for (int m = 0; m < 4; ++m) { post[m] = s_post[r][m]; prevpri[m] = s_prior[r][m]; }
#pragma unroll
            for (int m = 0; m < 4; ++m) {
                float s = 0.f;
#pragma unroll
                for (int j = 0; j < 4; ++j) s += Fm[m * 4 + j] * post[j];
                pri[m] = s;
            }
            float dy[2];
#pragma unroll
            for (int n = 0; n < 2; ++n) {
                float s = 0.f;
#pragma unroll
                for (int m = 0; m < 4; ++m) s += Hm[n * 4 + m] * pri[m];
                dy[n] = y[((size_t)t * BATCH + row0 + r) * 2 + n] - s;
            }
            float dx[4], ssx = 0.f;
#pragma unroll
            for (int m = 0; m < 4; ++m) { dx[m] = post[m] - prevpri[m]; ssx += dx[m] * dx[m]; }
            const float idx_ = rsqrtf(fmaxf(ssx, 1e-12f));
            const float idy_ = rsqrtf(fmaxf(dy[0] * dy[0] + dy[1] * dy[1], 1e-12f));
            s_in8[r][0] = dy[0] * idy_;
            s_in8[r][1] = dy[1] * idy_;
            s_in8[r][2] = dy[0] * idy_;
            s_in8[r][3] = dy[1] * idy_;
#pragma unroll
            for (int m = 0; m < 4; ++m) s_in8[r][4 + m] = dx[m] * idx_;
            s_dm1y[r][0] = dy[0];
            s_dm1y[r][1] = dy[1];
#pragma unroll
            for (int m = 0; m < 4; ++m) s_prior[r][m] = pri[m];
        }
        __syncthreads();

        // ---- Phase B: a1 = relu(in8 @ W1), split hi/lo into A-frag layout ----
        {
            const int m = tid & 15;
            float v8[8];
#pragma unroll
            for (int k = 0; k < 8; ++k) v8[k] = s_in8[m][k];
            for (int it = 0; it < 30; ++it) {
                const int j = (tid >> 4) + 16 * it;  // 0..479
                float s = b1[j];
#pragma unroll
                for (int k = 0; k < 8; ++k) s = fmaf(v8[k], W1[k * H1 + j], s);
                s = fmaxf(s, 0.f);
                const unsigned short hb = f2bf(s);
                const unsigned short lb = f2bf(s - bfu2f(hb));
                const int off = frag_off(j, m);
                a1h[off] = hb;
                a1l[off] = lb;
            }
        }
        __syncthreads();

        // ---- Phase C: GRU via MFMA. wave wv owns chunks wv, wv+4, wv+8(, wv+12) ----
        const f32x4 z4 = {0.f, 0.f, 0.f, 0.f};
        f32x4 az[4], ar4[4], ax[4], ah[4];
#pragma unroll
        for (int ci = 0; ci < 4; ++ci) { az[ci] = z4; ar4[ci] = z4; ax[ci] = z4; ah[ci] = z4; }
        const int nch = (wv == 0) ? 4 : 3;

        for (int s = 0; s < SL_X + SL_H; ++s) {
            const bool xs = (s < SL_X);
            const unsigned short* ph = xs ? (a1h + s * 512) : (hh_ + (s - SL_X) * 512);
            const unsigned short* pl = xs ? (a1l + s * 512) : (hl_ + (s - SL_X) * 512);
            const short8 Ahi = *(const short8*)(ph + lane * 8);
            const short8 Alo = *(const short8*)(pl + lane * 8);
            const int gstride = xs ? (15 * 512) : (7 * 512);
#pragma unroll
            for (int ci = 0; ci < 4; ++ci) {
                if (ci < nch) {
                    const int c = wv + 4 * ci;
                    const unsigned short* fb =
                        xs ? (WF + (size_t)(c * 45 + s) * 512)
                           : (UgF + (size_t)(c * 21 + (s - SL_X)) * 512);
                    const short8 B0 = *(const short8*)(fb + lane * 8);
                    const short8 B1 = *(const short8*)(fb + gstride + lane * 8);
                    const short8 B2 = *(const short8*)(fb + 2 * gstride + lane * 8);
                    az[ci]  = MFMA(Alo, B0, az[ci]);
                    az[ci]  = MFMA(Ahi, B0, az[ci]);
                    ar4[ci] = MFMA(Alo, B1, ar4[ci]);
                    ar4[ci] = MFMA(Ahi, B1, ar4[ci]);
                    if (xs) {
                        ax[ci] = MFMA(Alo, B2, ax[ci]);
                        ax[ci] = MFMA(Ahi, B2, ax[ci]);
                    } else {
                        ah[ci] = MFMA(Alo, B2, ah[ci]);
                        ah[ci] = MFMA(Ahi, B2, ah[ci]);
                    }
                }
            }
        }
        __syncthreads();  // all MFMA reads of a1F/hF done

        // gate nonlinearity + h update (C-layout: col=lane&15, row=(lane>>4)*4+i)
        for (int ci = 0; ci < nch; ++ci) {
            const int c  = wv + 4 * ci;
            const int jj = 16 * c + (lane & 15);
            if (jj < 200) {
                const float bz = s_bz[jj], br = s_br[jj], bx = s_bhx[jj], bh = s_bhh[jj];
#pragma unroll
                for (int i = 0; i < 4; ++i) {
                    const int m   = (lane >> 4) * 4 + i;
                    const int off = frag_off(jj, m);
                    const float hold = bfu2f(hh_[off]) + bfu2f(hl_[off]);
                    const float z  = sigmoid_(az[ci][i] + bz);
                    const float rr = sigmoid_(ar4[ci][i] + br);
                    const float hc = tanh_((ax[ci][i] + bx) + rr * (ah[ci][i] + bh));
                    const float hn = z * hold + (1.f - z) * hc;
                    const unsigned short hb = f2bf(hn);
                    const unsigned short lb = f2bf(hn - bfu2f(hb));
                    hh_[off] = hb;
                    hl_[off] = lb;
                }
            }
        }
        __syncthreads();  // h updated before Phase D reads it

        // ---- Phase D: a2 = relu(h @ W2) via MFMA; 5 N-tiles per wave ----
        f32x4 a2c[5];
#pragma unroll
        for (int k = 0; k < 5; ++k) a2c[k] = z4;
        for (int s = 0; s < SL_H; ++s) {
            const short8 Ahi = *(const short8*)(hh_ + s * 512 + lane * 8);
            const short8 Alo = *(const short8*)(hl_ + s * 512 + lane * 8);
#pragma unroll
            for (int k = 0; k < 5; ++k) {
                const int tl = wv + 4 * k;
                const short8 Bf = *(const short8*)(W2F + (size_t)(tl * 7 + s) * 512 + lane * 8);
                a2c[k] = MFMA(Alo, Bf, a2c[k]);
                a2c[k] = MFMA(Ahi, Bf, a2c[k]);
            }
        }
        // write a2 fp32 [n][m] (s_a2 unions a1F; a1F dead after Phase C barrier)
#pragma unroll
        for (int k = 0; k < 5; ++k) {
            const int n  = (wv + 4 * k) * 16 + (lane & 15);
            const float bb = b2[n];
            f32x4 o;
#pragma unroll
            for (int i = 0; i < 4; ++i) o[i] = fmaxf(a2c[k][i] + bb, 0.f);
            *(f32x4*)(s_a2 + n * 16 + (lane >> 4) * 4) = o;
        }
        __syncthreads();

        // ---- Phase E: KG = a2 @ W3 + b3 (VALU, 128 threads) ----
        if (tid < 128) {
            const int r = tid >> 3, c = tid & 7;
            float acc = b3[c];
            for (int k = 0; k < H2; ++k) acc = fmaf(s_a2[k * 16 + r], W3[k * 8 + c], acc);
            s_kg[r][c] = acc;
        }
        __syncthreads();

        // ---- Phase F: posterior update + output ----
        if (tid < 16) {
            const int r = tid;
            const float d0 = s_dm1y[r][0], d1 = s_dm1y[r][1];
            float p[4];
#pragma unroll
            for (int m = 0; m < 4; ++m) {
                p[m] = s_prior[r][m] + s_kg[r][2 * m] * d0 + s_kg[r][2 * m + 1] * d1;
                s_post[r][m] = p[m];
            }
            *reinterpret_cast<float4*>(&out[((size_t)t * BATCH + row0 + r) * 4]) =
                *reinterpret_cast<const float4*>(p);
        }
        __syncthreads();
    }
}

// ================= scalar fp32 fallback (R2-verified structure) =================
constexpr int FBR = 8;
__device__ __forceinline__ void load8f(const float* __restrict__ p, float* a) {
    const float4* v = reinterpret_cast<const float4*>(p);
    const float4 t0 = v[0], t1 = v[1];
    a[0] = t0.x; a[1] = t0.y; a[2] = t0.z; a[3] = t0.w;
    a[4] = t1.x; a[5] = t1.y; a[6] = t1.z; a[7] = t1.w;
}
__global__ __launch_bounds__(256, 4) void knet_fb(
    const float* __restrict__ y, const float* __restrict__ Fm, const float* __restrict__ Hm,
    const float* __restrict__ W1, const float* __restrict__ b1, const float* __restrict__ Wg,
    const float* __restrict__ Ug, const float* __restrict__ bg, const float* __restrict__ W2,
    const float* __restrict__ b2, const float* __restrict__ W3, const float* __restrict__ b3,
    const float* __restrict__ hn0, float* __restrict__ out) {
    __shared__ float s_hnt[HID][FBR];
    __shared__ float s_act[H1][FBR];
    __shared__ float s_in8[FBR][9], s_dm1y[FBR][2], s_prior[FBR][4], s_post[FBR][4], s_kg[FBR][8];
    const int tid = threadIdx.x;
    const int row0 = blockIdx.x * FBR;
    for (int idx = tid; idx < FBR * HID; idx += 256) {
        const int r = idx / HID, k = idx - r * HID;
        s_hnt[k][r] = hn0[(size_t)(row0 + r) * HID + k];
    }
    if (tid < FBR * 4) { s_prior[tid >> 2][tid & 3] = 0.f; s_post[tid >> 2][tid & 3] = 0.f; }
    __syncthreads();
    for (int t = 0; t < T_STEPS; ++t) {
        if (tid < FBR) {
            const int r = tid;
            float post[4], prevpri[4], pri[4];
            for (int m = 0; m < 4; ++m) { post[m] = s_post[r][m]; prevpri[m] = s_prior[r][m]; }
            for (int m = 0; m < 4; ++m) {
                float s = 0.f;
                for (int j = 0; j < 4; ++j) s += Fm[m * 4 + j] * post[j];
                pri[m] = s;
            }
            float dy[2];
            for (int n = 0; n < 2; ++n) {
                float s = 0.f;
                for (int m = 0; m < 4; ++m) s += Hm[n * 4 + m] * pri[m];
                dy[n] = y[((size_t)t * BATCH + row0 + r) * 2 + n] - s;
            }
            float dx[4], ssx = 0.f;
            for (int m = 0; m < 4; ++m) { dx[m] = post[m] - prevpri[m]; ssx += dx[m] * dx[m]; }
            const float idx_ = rsqrtf(fmaxf(ssx, 1e-12f));
            const float idy_ = rsqrtf(fmaxf(dy[0] * dy[0] + dy[1] * dy[1], 1e-12f));
            s_in8[r][0] = dy[0] * idy_; s_in8[r][1] = dy[1] * idy_;
            s_in8[r][2] = dy[0] * idy_; s_in8[r][3] = dy[1] * idy_;
            for (int m = 0; m < 4; ++m) s_in8[r][4 + m] = dx[m] * idx_;
            s_dm1y[r][0] = dy[0]; s_dm1y[r][1] = dy[1];
            for (int m = 0; m < 4; ++m) s_prior[r][m] = pri[m];
        }
        __syncthreads();
        {
            const int r = tid & (FBR - 1);
            float v[8];
            for (int k = 0; k < 8; ++k) v[k] = s_in8[r][k];
            for (int j = tid >> 3; j < H1; j += 32) {
                float s = b1[j];
                for (int k = 0; k < 8; ++k) s = fmaf(v[k], W1[k * H1 + j], s);
                s_act[j][r] = fmaxf(s, 0.f);
            }
        }
        __syncthreads();
        float hnew[FBR];
        if (tid < HID) {
            const int j = tid;
            float az[FBR], arr[FBR], ahx[FBR], ahh[FBR];
            for (int r = 0; r < FBR; ++r) { az[r] = arr[r] = ahx[r] = ahh[r] = 0.f; }
            for (int k = 0; k < H1; ++k) {
                const float wz = Wg[k * 600 + j], wr = Wg[k * 600 + j + HID], wh = Wg[k * 600 + j + 2 * HID];
                float a[FBR];
                load8f(&s_act[k][0], a);
                for (int r = 0; r < FBR; ++r) {
                    az[r] = fmaf(a[r], wz, az[r]); arr[r] = fmaf(a[r], wr, arr[r]); ahx[r] = fmaf(a[r], wh, ahx[r]);
                }
            }
            for (int k = 0; k < HID; ++k) {
                const float uz = Ug[k * 600 + j], ur = Ug[k * 600 + j + HID], uh = Ug[k * 600 + j + 2 * HID];
                float h[FBR];
                load8f(&s_hnt[k][0], h);
                for (int r = 0; r < FBR; ++r) {
                    az[r] = fmaf(h[r], uz, az[r]); arr[r] = fmaf(h[r], ur, arr[r]); ahh[r] = fmaf(h[r], uh, ahh[r]);
                }
            }
            const float bz = bg[j] + bg[600 + j], brr = bg[HID + j] + bg[600 + HID + j];
            const float bhx = bg[2 * HID + j], bhh = bg[600 + 2 * HID + j];
            float ho[FBR];
            load8f(&s_hnt[j][0], ho);
            for (int r = 0; r < FBR; ++r) {
                const float z = sigmoid_(az[r] + bz), rr = sigmoid_(arr[r] + brr);
                const float hc = tanh_((ahx[r] + bhx) + rr * (ahh[r] + bhh));
                hnew[r] = z * ho[r] + (1.f - z) * hc;
            }
        }
        __syncthreads();
        if (tid < HID) {
            float4* dst = reinterpret_cast<float4*>(&s_hnt[tid][0]);
            const float4* src = reinterpret_cast<const float4*>(hnew);
            dst[0] = src[0]; dst[1] = src[1];
        }
        __syncthreads();
        for (int j = tid; j < H2; j += 256) {
            float acc[FBR];
            for (int r = 0; r < FBR; ++r) acc[r] = 0.f;
            for (int k = 0; k < HID; ++k) {
                const float w = W2[k * H2 + j];
                float h[FBR];
                load8f(&s_hnt[k][0], h);
                for (int r = 0; r < FBR; ++r) acc[r] = fmaf(h[r], w, acc[r]);
            }
            for (int r = 0; r < FBR; ++r) s_act[j][r] = fmaxf(acc[r] + b2[j], 0.f);
        }
        __syncthreads();
        if (tid < FBR * 8) {
            const int r = tid >> 3, c = tid & 7;
            float acc = b3[c];
            for (int k = 0; k < H2; ++k) acc = fmaf(s_act[k][r], W3[k * 8 + c], acc);
            s_kg[r][c] = acc;
        }
        __syncthreads();
        if (tid < FBR) {
            const int r = tid;
            const float d0 = s_dm1y[r][0], d1 = s_dm1y[r][1];
            float p[4];
            for (int m = 0; m < 4; ++m) {
                p[m] = s_prior[r][m] + s_kg[r][2 * m] * d0 + s_kg[r][2 * m + 1] * d1;
                s_post[r][m] = p[m];
            }
            *reinterpret_cast<float4*>(&out[((size_t)t * BATCH + row0 + r) * 4]) =
                *reinterpret_cast<const float4*>(p);
        }
        __syncthreads();
    }
}

}  // namespace

extern "C" void kernel_launch(void* const* d_in, const int* in_sizes, int n_in,
                              void* d_out, int out_size, void* d_ws, size_t ws_size,
                              hipStream_t stream) {
    const float* y   = (const float*)d_in[0];
    const float* Fm  = (const float*)d_in[1];
    const float* Hm  = (const float*)d_in[2];
    const float* W1  = (const float*)d_in[3];
    const float* b1  = (const float*)d_in[4];
    const float* Wg  = (const float*)d_in[5];
    const float* Ug  = (const float*)d_in[6];
    const float* bg  = (const float*)d_in[7];
    const float* W2  = (const float*)d_in[8];
    const float* b2  = (const float*)d_in[9];
    const float* W3  = (const float*)d_in[10];
    const float* b3  = (const float*)d_in[11];
    const float* hn0 = (const float*)d_in[12];
    float* out = (float*)d_out;

    if (ws_size >= WS_NEED) {
        unsigned short* WFr = (unsigned short*)d_ws;
        cvt_kernel<<<(FRAGS * 512 + 255) / 256, 256, 0, stream>>>(Wg, Ug, W2, WFr);
        knet_mfma<<<dim3(BATCH / BR), dim3(NTHR), 0, stream>>>(
            y, Fm, Hm, W1, b1, bg, b2, W3, b3, hn0, WFr, out);
    } else {
        knet_fb<<<dim3(BATCH / FBR), dim3(256), 0, stream>>>(
            y, Fm, Hm, W1, b1, Wg, Ug, bg, W2, b2, W3, b3, hn0, out);
    }
}

// Round 5
// 5904.636 us; speedup vs baseline: 1.2561x; 1.2561x over previous
//
#include <hip/hip_runtime.h>

namespace {

constexpr int T_STEPS = 32;
constexpr int BATCH   = 8192;
constexpr int H1      = 480;
constexpr int HID     = 200;
constexpr int H2      = 320;
constexpr int BR      = 16;    // rows per block = one MFMA M-tile
constexpr int NTHR    = 256;   // 4 waves

constexpr int NCH   = 16;      // N chunks of 16 (200 padded to 256)
constexpr int SL_X  = 15;      // K-slices of 32 for a1 (480)
constexpr int SL_H  = 8;       // K-slices for h (200 padded to 256)
constexpr int FR_WG = NCH * 3 * SL_X;       // 720
constexpr int FR_UG = NCH * 3 * SL_H;       // 384
constexpr int FR_W2 = (H2 / 16) * SL_H;     // 160
constexpr int FRAGS = FR_WG + FR_UG + FR_W2;  // 1264
constexpr size_t WS_NEED = (size_t)FRAGS * 512 * 2;

typedef short  short8 __attribute__((ext_vector_type(8)));
typedef float  f32x4  __attribute__((ext_vector_type(4)));

__device__ __forceinline__ unsigned short f2bf(float x) {
    unsigned u = __float_as_uint(x);
    u = (u + 0x7fffu + ((u >> 16) & 1u)) >> 16;
    return (unsigned short)u;
}
__device__ __forceinline__ float bfu2f(unsigned short b) {
    return __uint_as_float(((unsigned)b) << 16);
}
__device__ __forceinline__ float sigmoid_(float x) { return 1.f / (1.f + __expf(-x)); }
__device__ __forceinline__ float tanh_(float x) {
    x = fminf(fmaxf(x, -15.f), 15.f);
    const float e = __expf(-2.f * x);
    return (1.f - e) / (1.f + e);
}
__device__ __forceinline__ f32x4 MFMA(short8 a, short8 b, f32x4 c) {
    return __builtin_amdgcn_mfma_f32_16x16x32_bf16(a, b, c, 0, 0, 0);
}
// element offset of (k, m-or-n) in slice-linear A/B fragment storage
__device__ __forceinline__ int frag_off(int k, int m) {
    return ((k >> 5) * 64 + ((k & 31) >> 3) * 16 + m) * 8 + (k & 7);
}

// ---- prep: rearrange Wg/Ug/W2 to bf16 B-frag-linear layout in d_ws ----
// WgF: [c 16][g 3][s 15][512] ; UgF: [c 16][g 3][s 8][512] ; W2F: [t 20][s 8][512]
__global__ void cvt_kernel(const float* __restrict__ Wg, const float* __restrict__ Ug,
                           const float* __restrict__ W2, unsigned short* __restrict__ o) {
    const int i = blockIdx.x * 256 + threadIdx.x;
    if (i >= FRAGS * 512) return;
    const int f = i >> 9, e = i & 511;
    const int l = e >> 3, j = e & 7;
    const int nn = l & 15, q = l >> 4;
    float v = 0.f;
    if (f < FR_WG) {
        const int c = f / 45, r = f % 45, g = r / 15, s = r % 15;
        const int n = 16 * c + nn, k = 32 * s + 8 * q + j;
        if (n < 200) v = Wg[k * 600 + g * 200 + n];
    } else if (f < FR_WG + FR_UG) {
        const int f2 = f - FR_WG, c = f2 / 24, r = f2 % 24, g = r / 8, s = r % 8;
        const int n = 16 * c + nn, k = 32 * s + 8 * q + j;
        if (n < 200 && k < 200) v = Ug[k * 600 + g * 200 + n];
    } else {
        const int f3 = f - FR_WG - FR_UG, tt = f3 / 8, s = f3 % 8;
        const int n = 16 * tt + nn, k = 32 * s + 8 * q + j;
        if (k < 200) v = W2[k * 320 + n];
    }
    o[i] = f2bf(v);
}

__global__ __launch_bounds__(NTHR, 2) void knet_mfma(
    const float* __restrict__ y,    // [T,B,2]
    const float* __restrict__ Fm,   // [4,4]
    const float* __restrict__ Hm,   // [2,4]
    const float* __restrict__ W1,   // [8,480]
    const float* __restrict__ b1,   // [480]
    const float* __restrict__ bg,   // [2,600]
    const float* __restrict__ b2,   // [320]
    const float* __restrict__ W3,   // [320,8]
    const float* __restrict__ b3,   // [8]
    const float* __restrict__ hn0,  // [B,200]
    const unsigned short* __restrict__ WF,
    float* __restrict__ out)        // [T,B,4]
{
    __shared__ __align__(16) unsigned short s_a1f[2 * SL_X * 512];  // 30720 B (a2 unions)
    __shared__ __align__(16) unsigned short s_hf[2 * SL_H * 512];   // 16384 B
    __shared__ float s_bz[208], s_br[208], s_bhx[208], s_bhh[208];
    __shared__ float s_in8[16][9];
    __shared__ float s_dm1y[16][2], s_prior[16][4], s_post[16][4], s_kg[16][8];

    const int tid  = threadIdx.x;
    const int lane = tid & 63, wv = tid >> 6;
    const int row0 = blockIdx.x * BR;

    unsigned short* a1h = s_a1f;
    unsigned short* a1l = s_a1f + SL_X * 512;
    unsigned short* hh_ = s_hf;
    unsigned short* hl_ = s_hf + SL_H * 512;
    float* s_a2 = (float*)s_a1f;  // union (a1 frags dead when a2 written)

    const unsigned short* UgF = WF + (size_t)FR_WG * 512;
    const unsigned short* W2F = WF + (size_t)(FR_WG + FR_UG) * 512;

    // ---- init ----
    for (int t = tid; t < 208; t += NTHR) {
        const bool v = t < 200;
        s_bz[t]  = v ? bg[t] + bg[600 + t] : 0.f;
        s_br[t]  = v ? bg[200 + t] + bg[800 + t] : 0.f;
        s_bhx[t] = v ? bg[400 + t] : 0.f;
        s_bhh[t] = v ? bg[1000 + t] : 0.f;
    }
    for (int i = tid; i < 256 * 16; i += NTHR) {  // h0 -> hi/lo frags (+zero pad)
        const int k = i >> 4, m = i & 15;
        const float hv = (k < 200) ? hn0[(size_t)(row0 + m) * HID + k] : 0.f;
        const unsigned short hb = f2bf(hv);
        const unsigned short lb = f2bf(hv - bfu2f(hb));
        const int off = frag_off(k, m);
        hh_[off] = hb;
        hl_[off] = lb;
    }
    if (tid < 64) {
        s_prior[tid >> 2][tid & 3] = 0.f;
        s_post[tid >> 2][tid & 3]  = 0.f;
    }
    __syncthreads();

    const int c0    = wv * 4;            // 4 contiguous N-chunks per wave
    const int laneo = lane * 8;

    for (int t = 0; t < T_STEPS; ++t) {
        // ---- Phase A: prior / innovation / features (16 threads) ----
        if (tid < 16) {
            const int r = tid;
            float post[4], prevpri[4], pri[4];
#pragma unroll
            for (int m = 0; m < 4; ++m) { post[m] = s_post[r][m]; prevpri[m] = s_prior[r][m]; }
#pragma unroll
            for (int m = 0; m < 4; ++m) {
                float s = 0.f;
#pragma unroll
                for (int j = 0; j < 4; ++j) s += Fm[m * 4 + j] * post[j];
                pri[m] = s;
            }
            float dy[2];
#pragma unroll
            for (int n = 0; n < 2; ++n) {
                float s = 0.f;
#pragma unroll
                for (int m = 0; m < 4; ++m) s += Hm[n * 4 + m] * pri[m];
                dy[n] = y[((size_t)t * BATCH + row0 + r) * 2 + n] - s;
            }
            float dx[4], ssx = 0.f;
#pragma unroll
            for (int m = 0; m < 4; ++m) { dx[m] = post[m] - prevpri[m]; ssx += dx[m] * dx[m]; }
            const float idx_ = rsqrtf(fmaxf(ssx, 1e-12f));
            const float idy_ = rsqrtf(fmaxf(dy[0] * dy[0] + dy[1] * dy[1], 1e-12f));
            s_in8[r][0] = dy[0] * idy_;
            s_in8[r][1] = dy[1] * idy_;
            s_in8[r][2] = dy[0] * idy_;
            s_in8[r][3] = dy[1] * idy_;
#pragma unroll
            for (int m = 0; m < 4; ++m) s_in8[r][4 + m] = dx[m] * idx_;
            s_dm1y[r][0] = dy[0];
            s_dm1y[r][1] = dy[1];
#pragma unroll
            for (int m = 0; m < 4; ++m) s_prior[r][m] = pri[m];
        }
        __syncthreads();

        // ---- Phase B: a1 = relu(in8 @ W1), hi/lo split into A-frag layout ----
        {
            const int m = tid & 15;
            float v8[8];
#pragma unroll
            for (int k = 0; k < 8; ++k) v8[k] = s_in8[m][k];
            for (int it = 0; it < 30; ++it) {
                const int j = (tid >> 4) + 16 * it;  // 0..479
                float s = b1[j];
#pragma unroll
                for (int k = 0; k < 8; ++k) s = fmaf(v8[k], W1[k * H1 + j], s);
                s = fmaxf(s, 0.f);
                const unsigned short hb = f2bf(s);
                const unsigned short lb = f2bf(s - bfu2f(hb));
                const int off = frag_off(j, m);
                a1h[off] = hb;
                a1l[off] = lb;
            }
        }
        __syncthreads();

        // ---- Phase C: GRU via MFMA, uniform 4 chunks/wave, no guards ----
        const f32x4 zero4 = {0.f, 0.f, 0.f, 0.f};
        f32x4 az[4], ar4[4], ax[4];
#pragma unroll
        for (int ci = 0; ci < 4; ++ci) { az[ci] = zero4; ar4[ci] = zero4; ax[ci] = zero4; }

        for (int s = 0; s < SL_X; ++s) {  // x-part: K = 480
            const short8 Ahi = *(const short8*)(a1h + s * 512 + laneo);
            const short8 Alo = *(const short8*)(a1l + s * 512 + laneo);
#pragma unroll
            for (int ci = 0; ci < 4; ++ci) {
                const unsigned short* fb = WF + (size_t)(((c0 + ci) * 3) * SL_X + s) * 512 + laneo;
                const short8 B0 = *(const short8*)(fb);
                const short8 B1 = *(const short8*)(fb + SL_X * 512);
                const short8 B2 = *(const short8*)(fb + 2 * SL_X * 512);
                az[ci]  = MFMA(Alo, B0, az[ci]);
                az[ci]  = MFMA(Ahi, B0, az[ci]);
                ar4[ci] = MFMA(Alo, B1, ar4[ci]);
                ar4[ci] = MFMA(Ahi, B1, ar4[ci]);
                ax[ci]  = MFMA(Alo, B2, ax[ci]);
                ax[ci]  = MFMA(Ahi, B2, ax[ci]);
            }
        }

        f32x4 ah[4];
#pragma unroll
        for (int ci = 0; ci < 4; ++ci) ah[ci] = zero4;
        for (int s = 0; s < SL_H; ++s) {  // h-part: K = 256 (padded)
            const short8 Ahi = *(const short8*)(hh_ + s * 512 + laneo);
            const short8 Alo = *(const short8*)(hl_ + s * 512 + laneo);
#pragma unroll
            for (int ci = 0; ci < 4; ++ci) {
                const unsigned short* fb = UgF + (size_t)(((c0 + ci) * 3) * SL_H + s) * 512 + laneo;
                const short8 B0 = *(const short8*)(fb);
                const short8 B1 = *(const short8*)(fb + SL_H * 512);
                const short8 B2 = *(const short8*)(fb + 2 * SL_H * 512);
                az[ci]  = MFMA(Alo, B0, az[ci]);
                az[ci]  = MFMA(Ahi, B0, az[ci]);
                ar4[ci] = MFMA(Alo, B1, ar4[ci]);
                ar4[ci] = MFMA(Ahi, B1, ar4[ci]);
                ah[ci]  = MFMA(Alo, B2, ah[ci]);
                ah[ci]  = MFMA(Ahi, B2, ah[ci]);
            }
        }
        __syncthreads();  // all MFMA reads of a1F/hF done

        // gate nonlinearity + h update (C-layout: col=lane&15, row=(lane>>4)*4+i)
#pragma unroll
        for (int ci = 0; ci < 4; ++ci) {
            const int jj = 16 * (c0 + ci) + (lane & 15);
            if (jj < 200) {  // padded columns stay 0 from init
                const float bz = s_bz[jj], br = s_br[jj], bx = s_bhx[jj], bh = s_bhh[jj];
#pragma unroll
                for (int i = 0; i < 4; ++i) {
                    const int m   = (lane >> 4) * 4 + i;
                    const int off = frag_off(jj, m);
                    const float hold = bfu2f(hh_[off]) + bfu2f(hl_[off]);
                    const float z  = sigmoid_(az[ci][i] + bz);
                    const float rr = sigmoid_(ar4[ci][i] + br);
                    const float hc = tanh_((ax[ci][i] + bx) + rr * (ah[ci][i] + bh));
                    const float hn = z * hold + (1.f - z) * hc;
                    const unsigned short hb = f2bf(hn);
                    const unsigned short lb = f2bf(hn - bfu2f(hb));
                    hh_[off] = hb;
                    hl_[off] = lb;
                }
            }
        }
        __syncthreads();  // h updated before Phase D reads it

        // ---- Phase D: a2 = relu(h @ W2) via MFMA; 5 N-tiles per wave ----
        f32x4 a2c[5];
#pragma unroll
        for (int k = 0; k < 5; ++k) a2c[k] = zero4;
        for (int s = 0; s < SL_H; ++s) {
            const short8 Ahi = *(const short8*)(hh_ + s * 512 + laneo);
            const short8 Alo = *(const short8*)(hl_ + s * 512 + laneo);
#pragma unroll
            for (int k = 0; k < 5; ++k) {
                const int tl = wv + 4 * k;
                const short8 Bf = *(const short8*)(W2F + (size_t)(tl * SL_H + s) * 512 + laneo);
                a2c[k] = MFMA(Alo, Bf, a2c[k]);
                a2c[k] = MFMA(Ahi, Bf, a2c[k]);
            }
        }
#pragma unroll
        for (int k = 0; k < 5; ++k) {  // a2 fp32 [n][m] into the a1F union
            const int n  = (wv + 4 * k) * 16 + (lane & 15);
            const float bb = b2[n];
            f32x4 o;
#pragma unroll
            for (int i = 0; i < 4; ++i) o[i] = fmaxf(a2c[k][i] + bb, 0.f);
            *(f32x4*)(s_a2 + n * 16 + (lane >> 4) * 4) = o;
        }
        __syncthreads();

        // ---- Phase E: KG = a2 @ W3 + b3 (VALU, 128 threads) ----
        if (tid < 128) {
            const int r = tid >> 3, c = tid & 7;
            float acc = b3[c];
            for (int k = 0; k < H2; ++k) acc = fmaf(s_a2[k * 16 + r], W3[k * 8 + c], acc);
            s_kg[r][c] = acc;
        }
        __syncthreads();

        // ---- Phase F: posterior update + output ----
        if (tid < 16) {
            const int r = tid;
            const float d0 = s_dm1y[r][0], d1 = s_dm1y[r][1];
            float p[4];
#pragma unroll
            for (int m = 0; m < 4; ++m) {
                p[m] = s_prior[r][m] + s_kg[r][2 * m] * d0 + s_kg[r][2 * m + 1] * d1;
                s_post[r][m] = p[m];
            }
            *reinterpret_cast<float4*>(&out[((size_t)t * BATCH + row0 + r) * 4]) =
                *reinterpret_cast<const float4*>(p);
        }
        __syncthreads();
    }
}

// ================= scalar fp32 fallback (R2-verified structure) =================
constexpr int FBR = 8;
__device__ __forceinline__ void load8f(const float* __restrict__ p, float* a) {
    const float4* v = reinterpret_cast<const float4*>(p);
    const float4 t0 = v[0], t1 = v[1];
    a[0] = t0.x; a[1] = t0.y; a[2] = t0.z; a[3] = t0.w;
    a[4] = t1.x; a[5] = t1.y; a[6] = t1.z; a[7] = t1.w;
}
__global__ __launch_bounds__(256, 4) void knet_fb(
    const float* __restrict__ y, const float* __restrict__ Fm, const float* __restrict__ Hm,
    const float* __restrict__ W1, const float* __restrict__ b1, const float* __restrict__ Wg,
    const float* __restrict__ Ug, const float* __restrict__ bg, const float* __restrict__ W2,
    const float* __restrict__ b2, const float* __restrict__ W3, const float* __restrict__ b3,
    const float* __restrict__ hn0, float* __restrict__ out) {
    __shared__ float s_hnt[HID][FBR];
    __shared__ float s_act[H1][FBR];
    __shared__ float s_in8[FBR][9], s_dm1y[FBR][2], s_prior[FBR][4], s_post[FBR][4], s_kg[FBR][8];
    const int tid = threadIdx.x;
    const int row0 = blockIdx.x * FBR;
    for (int idx = tid; idx < FBR * HID; idx += 256) {
        const int r = idx / HID, k = idx - r * HID;
        s_hnt[k][r] = hn0[(size_t)(row0 + r) * HID + k];
    }
    if (tid < FBR * 4) { s_prior[tid >> 2][tid & 3] = 0.f; s_post[tid >> 2][tid & 3] = 0.f; }
    __syncthreads();
    for (int t = 0; t < T_STEPS; ++t) {
        if (tid < FBR) {
            const int r = tid;
            float post[4], prevpri[4], pri[4];
            for (int m = 0; m < 4; ++m) { post[m] = s_post[r][m]; prevpri[m] = s_prior[r][m]; }
            for (int m = 0; m < 4; ++m) {
                float s = 0.f;
                for (int j = 0; j < 4; ++j) s += Fm[m * 4 + j] * post[j];
                pri[m] = s;
            }
            float dy[2];
            for (int n = 0; n < 2; ++n) {
                float s = 0.f;
                for (int m = 0; m < 4; ++m) s += Hm[n * 4 + m] * pri[m];
                dy[n] = y[((size_t)t * BATCH + row0 + r) * 2 + n] - s;
            }
            float dx[4], ssx = 0.f;
            for (int m = 0; m < 4; ++m) { dx[m] = post[m] - prevpri[m]; ssx += dx[m] * dx[m]; }
            const float idx_ = rsqrtf(fmaxf(ssx, 1e-12f));
            const float idy_ = rsqrtf(fmaxf(dy[0] * dy[0] + dy[1] * dy[1], 1e-12f));
            s_in8[r][0] = dy[0] * idy_; s_in8[r][1] = dy[1] * idy_;
            s_in8[r][2] = dy[0] * idy_; s_in8[r][3] = dy[1] * idy_;
            for (int m = 0; m < 4; ++m) s_in8[r][4 + m] = dx[m] * idx_;
            s_dm1y[r][0] = dy[0]; s_dm1y[r][1] = dy[1];
            for (int m = 0; m < 4; ++m) s_prior[r][m] = pri[m];
        }
        __syncthreads();
        {
            const int r = tid & (FBR - 1);
            float v[8];
            for (int k = 0; k < 8; ++k) v[k] = s_in8[r][k];
            for (int j = tid >> 3; j < H1; j += 32) {
                float s = b1[j];
                for (int k = 0; k < 8; ++k) s = fmaf(v[k], W1[k * H1 + j], s);
                s_act[j][r] = fmaxf(s, 0.f);
            }
        }
        __syncthreads();
        float hnew[FBR];
        if (tid < HID) {
            const int j = tid;
            float az[FBR], arr[FBR], ahx[FBR], ahh[FBR];
            for (int r = 0; r < FBR; ++r) { az[r] = arr[r] = ahx[r] = ahh[r] = 0.f; }
            for (int k = 0; k < H1; ++k) {
                const float wz = Wg[k * 600 + j], wr = Wg[k * 600 + j + HID], wh = Wg[k * 600 + j + 2 * HID];
                float a[FBR];
                load8f(&s_act[k][0], a);
                for (int r = 0; r < FBR; ++r) {
                    az[r] = fmaf(a[r], wz, az[r]); arr[r] = fmaf(a[r], wr, arr[r]); ahx[r] = fmaf(a[r], wh, ahx[r]);
                }
            }
            for (int k = 0; k < HID; ++k) {
                const float uz = Ug[k * 600 + j], ur = Ug[k * 600 + j + HID], uh = Ug[k * 600 + j + 2 * HID];
                float h[FBR];
                load8f(&s_hnt[k][0], h);
                for (int r = 0; r < FBR; ++r) {
                    az[r] = fmaf(h[r], uz, az[r]); arr[r] = fmaf(h[r], ur, arr[r]); ahh[r] = fmaf(h[r], uh, ahh[r]);
                }
            }
            const float bz = bg[j] + bg[600 + j], brr = bg[HID + j] + bg[600 + HID + j];
            const float bhx = bg[2 * HID + j], bhh = bg[600 + 2 * HID + j];
            float ho[FBR];
            load8f(&s_hnt[j][0], ho);
            for (int r = 0; r < FBR; ++r) {
                const float z = sigmoid_(az[r] + bz), rr = sigmoid_(arr[r] + brr);
                const float hc = tanh_((ahx[r] + bhx) + rr * (ahh[r] + bhh));
                hnew[r] = z * ho[r] + (1.f - z) * hc;
            }
        }
        __syncthreads();
        if (tid < HID) {
            float4* dst = reinterpret_cast<float4*>(&s_hnt[tid][0]);
            const float4* src = reinterpret_cast<const float4*>(hnew);
            dst[0] = src[0]; dst[1] = src[1];
        }
        __syncthreads();
        for (int j = tid; j < H2; j += 256) {
            float acc[FBR];
            for (int r = 0; r < FBR; ++r) acc[r] = 0.f;
            for (int k = 0; k < HID; ++k) {
                const float w = W2[k * H2 + j];
                float h[FBR];
                load8f(&s_hnt[k][0], h);
                for (int r = 0; r < FBR; ++r) acc[r] = fmaf(h[r], w, acc[r]);
            }
            for (int r = 0; r < FBR; ++r) s_act[j][r] = fmaxf(acc[r] + b2[j], 0.f);
        }
        __syncthreads();
        if (tid < FBR * 8) {
            const int r = tid >> 3, c = tid & 7;
            float acc = b3[c];
            for (int k = 0; k < H2; ++k) acc = fmaf(s_act[k][r], W3[k * 8 + c], acc);
            s_kg[r][c] = acc;
        }
        __syncthreads();
        if (tid < FBR) {
            const int r = tid;
            const float d0 = s_dm1y[r][0], d1 = s_dm1y[r][1];
            float p[4];
            for (int m = 0; m < 4; ++m) {
                p[m] = s_prior[r][m] + s_kg[r][2 * m] * d0 + s_kg[r][2 * m + 1] * d1;
                s_post[r][m] = p[m];
            }
            *reinterpret_cast<float4*>(&out[((size_t)t * BATCH + row0 + r) * 4]) =
                *reinterpret_cast<const float4*>(p);
        }
        __syncthreads();
    }
}

}  // namespace

extern "C" void kernel_launch(void* const* d_in, const int* in_sizes, int n_in,
                              void* d_out, int out_size, void* d_ws, size_t ws_size,
                              hipStream_t stream) {
    const float* y   = (const float*)d_in[0];
    const float* Fm  = (const float*)d_in[1];
    const float* Hm  = (const float*)d_in[2];
    const float* W1  = (const float*)d_in[3];
    const float* b1  = (const float*)d_in[4];
    const float* Wg  = (const float*)d_in[5];
    const float* Ug  = (const float*)d_in[6];
    const float* bg  = (const float*)d_in[7];
    const float* W2  = (const float*)d_in[8];
    const float* b2  = (const float*)d_in[9];
    const float* W3  = (const float*)d_in[10];
    const float* b3  = (const float*)d_in[11];
    const float* hn0 = (const float*)d_in[12];
    float* out = (float*)d_out;

    if (ws_size >= WS_NEED) {
        unsigned short* WFr = (unsigned short*)d_ws;
        cvt_kernel<<<(FRAGS * 512 + 255) / 256, 256, 0, stream>>>(Wg, Ug, W2, WFr);
        knet_mfma<<<dim3(BATCH / BR), dim3(NTHR), 0, stream>>>(
            y, Fm, Hm, W1, b1, bg, b2, W3, b3, hn0, WFr, out);
    } else {
        knet_fb<<<dim3(BATCH / FBR), dim3(256), 0, stream>>>(
            y, Fm, Hm, W1, b1, Wg, Ug, bg, W2, b2, W3, b3, hn0, out);
    }
}

// Round 6
// 4583.297 us; speedup vs baseline: 1.6182x; 1.2883x over previous
//
#include <hip/hip_runtime.h>

namespace {

constexpr int T_STEPS = 32;
constexpr int BATCH   = 8192;
constexpr int H1      = 480;
constexpr int HID     = 200;
constexpr int H2      = 320;
constexpr int BR      = 16;    // rows per block = one MFMA M-tile
constexpr int NTHR    = 256;   // 4 waves

constexpr int NCH   = 13;      // 16-col chunks covering 208 (>= HID)
constexpr int SL_X  = 15;      // K-slices of 32 for x-part (480)
constexpr int SL_H  = 7;       // K-slices for h-part (224 >= HID)
constexpr int FR_WG = 3 * NCH * SL_X;       // 585
constexpr int FR_UG = 3 * NCH * SL_H;       // 273
constexpr int FR_W2 = (H2 / 16) * SL_H;     // 140
constexpr int FRAGS = FR_WG + FR_UG + FR_W2;  // 998
constexpr size_t WS_NEED = (size_t)FRAGS * 512 * 2;

typedef short  short8 __attribute__((ext_vector_type(8)));
typedef float  f32x4  __attribute__((ext_vector_type(4)));

__device__ __forceinline__ unsigned short f2bf(float x) {
    unsigned u = __float_as_uint(x);
    u = (u + 0x7fffu + ((u >> 16) & 1u)) >> 16;
    return (unsigned short)u;
}
__device__ __forceinline__ float bfu2f(unsigned short b) {
    return __uint_as_float(((unsigned)b) << 16);
}
__device__ __forceinline__ float sigmoid_(float x) { return 1.f / (1.f + __expf(-x)); }
__device__ __forceinline__ float tanh_(float x) {
    x = fminf(fmaxf(x, -15.f), 15.f);
    const float e = __expf(-2.f * x);
    return (1.f - e) / (1.f + e);
}
__device__ __forceinline__ f32x4 MFMA(short8 a, short8 b, f32x4 c) {
    return __builtin_amdgcn_mfma_f32_16x16x32_bf16(a, b, c, 0, 0, 0);
}
// element offset of (k, m-or-n) in slice-linear A/B fragment storage
__device__ __forceinline__ int frag_off(int k, int m) {
    return ((k >> 5) * 64 + ((k & 31) >> 3) * 16 + m) * 8 + (k & 7);
}

// ---- prep: rearrange Wg/Ug/W2 to bf16 B-frag-linear layout in d_ws ----
// WgF: [(g*13+c)*15+s][512] ; UgF: [(g*13+c)*7+s][512] ; W2F: [t*7+s][512]
__global__ void cvt_kernel(const float* __restrict__ Wg, const float* __restrict__ Ug,
                           const float* __restrict__ W2, unsigned short* __restrict__ o) {
    const int i = blockIdx.x * 256 + threadIdx.x;
    if (i >= FRAGS * 512) return;
    const int f = i >> 9, e = i & 511;
    const int l = e >> 3, j = e & 7;
    const int nn = l & 15, q = l >> 4;
    float v = 0.f;
    if (f < FR_WG) {
        const int g = f / (NCH * SL_X), r = f % (NCH * SL_X), c = r / SL_X, s = r % SL_X;
        const int n = 16 * c + nn, k = 32 * s + 8 * q + j;
        if (n < 200) v = Wg[k * 600 + g * 200 + n];
    } else if (f < FR_WG + FR_UG) {
        const int f2 = f - FR_WG;
        const int g = f2 / (NCH * SL_H), r = f2 % (NCH * SL_H), c = r / SL_H, s = r % SL_H;
        const int n = 16 * c + nn, k = 32 * s + 8 * q + j;
        if (n < 200 && k < 200) v = Ug[k * 600 + g * 200 + n];
    } else {
        const int f3 = f - FR_WG - FR_UG, tl = f3 / SL_H, s = f3 % SL_H;
        const int n = 16 * tl + nn, k = 32 * s + 8 * q + j;
        if (k < 200) v = W2[k * 320 + n];
    }
    o[i] = f2bf(v);
}

__global__ __launch_bounds__(NTHR, 2) void knet_mfma(
    const float* __restrict__ y,    // [T,B,2]
    const float* __restrict__ Fm,   // [4,4]
    const float* __restrict__ Hm,   // [2,4]
    const float* __restrict__ W1,   // [8,480]
    const float* __restrict__ b1,   // [480]
    const float* __restrict__ bg,   // [2,600]
    const float* __restrict__ b2,   // [320]
    const float* __restrict__ W3,   // [320,8]
    const float* __restrict__ b3,   // [8]
    const float* __restrict__ hn0,  // [B,200]
    const unsigned short* __restrict__ WF,
    float* __restrict__ out)        // [T,B,4]
{
    __shared__ __align__(16) unsigned short s_a1f[2 * SL_X * 512];  // 30720 B
    __shared__ __align__(16) unsigned short s_hf[2 * SL_H * 512];   // 14336 B
    __shared__ __align__(16) float s_zr[2][16][212];                // 27136 B (a2 unions)
    __shared__ float s_bz[208], s_br[208], s_bhx[208], s_bhh[208];
    __shared__ float s_b2[H2];
    __shared__ float s_in8[16][9];
    __shared__ float s_dm1y[16][2], s_prior[16][4], s_post[16][4], s_kg[16][8];

    const int tid  = threadIdx.x;
    const int lane = tid & 63, wv = tid >> 6;
    const int row0 = blockIdx.x * BR;

    unsigned short* a1h = s_a1f;
    unsigned short* a1l = s_a1f + SL_X * 512;
    unsigned short* hh_ = s_hf;
    unsigned short* hl_ = s_hf + SL_H * 512;
    float* s_a2 = &s_zr[0][0][0];  // union: 320*16 fp32 = 20480 B <= 27136 B

    const unsigned short* UgF = WF + (size_t)FR_WG * 512;
    const unsigned short* W2F = WF + (size_t)(FR_WG + FR_UG) * 512;

    // ---- init ----
    for (int t = tid; t < 208; t += NTHR) {
        const bool v = t < 200;
        s_bz[t]  = v ? bg[t] + bg[600 + t] : 0.f;
        s_br[t]  = v ? bg[200 + t] + bg[800 + t] : 0.f;
        s_bhx[t] = v ? bg[400 + t] : 0.f;
        s_bhh[t] = v ? bg[1000 + t] : 0.f;
    }
    for (int t = tid; t < H2; t += NTHR) s_b2[t] = b2[t];
    for (int i = tid; i < 224 * 16; i += NTHR) {  // h0 -> hi/lo frags (+zero K-pad)
        const int k = i >> 4, m = i & 15;
        const float hv = (k < 200) ? hn0[(size_t)(row0 + m) * HID + k] : 0.f;
        const unsigned short hb = f2bf(hv);
        const int off = frag_off(k, m);
        hh_[off] = hb;
        hl_[off] = f2bf(hv - bfu2f(hb));
    }
    if (tid < 64) {
        s_prior[tid >> 2][tid & 3] = 0.f;
        s_post[tid >> 2][tid & 3]  = 0.f;
    }
    __syncthreads();

    const int laneo = lane * 8;
    const f32x4 zero4 = {0.f, 0.f, 0.f, 0.f};

    for (int t = 0; t < T_STEPS; ++t) {
        // ---- Phase A: prior / innovation / features (16 threads) ----
        if (tid < 16) {
            const int r = tid;
            float post[4], prevpri[4], pri[4];
#pragma unroll
            for (int m = 0; m < 4; ++m) { post[m] = s_post[r][m]; prevpri[m] = s_prior[r][m]; }
#pragma unroll
            for (int m = 0; m < 4; ++m) {
                float s = 0.f;
#pragma unroll
                for (int j = 0; j < 4; ++j) s += Fm[m * 4 + j] * post[j];
                pri[m] = s;
            }
            float dy[2];
#pragma unroll
            for (int n = 0; n < 2; ++n) {
                float s = 0.f;
#pragma unroll
                for (int m = 0; m < 4; ++m) s += Hm[n * 4 + m] * pri[m];
                dy[n] = y[((size_t)t * BATCH + row0 + r) * 2 + n] - s;
            }
            float dx[4], ssx = 0.f;
#pragma unroll
            for (int m = 0; m < 4; ++m) { dx[m] = post[m] - prevpri[m]; ssx += dx[m] * dx[m]; }
            const float idx_ = rsqrtf(fmaxf(ssx, 1e-12f));
            const float idy_ = rsqrtf(fmaxf(dy[0] * dy[0] + dy[1] * dy[1], 1e-12f));
            s_in8[r][0] = dy[0] * idy_;
            s_in8[r][1] = dy[1] * idy_;
            s_in8[r][2] = dy[0] * idy_;
            s_in8[r][3] = dy[1] * idy_;
#pragma unroll
            for (int m = 0; m < 4; ++m) s_in8[r][4 + m] = dx[m] * idx_;
            s_dm1y[r][0] = dy[0];
            s_dm1y[r][1] = dy[1];
#pragma unroll
            for (int m = 0; m < 4; ++m) s_prior[r][m] = pri[m];
        }
        __syncthreads();

        // ---- Phase B: a1 = relu(in8 @ W1), hi/lo split into A-frag layout ----
        {
            const int m = tid & 15;
            float v8[8];
#pragma unroll
            for (int k = 0; k < 8; ++k) v8[k] = s_in8[m][k];
            for (int it = 0; it < 30; ++it) {
                const int j = (tid >> 4) + 16 * it;  // 0..479
                float s = b1[j];
#pragma unroll
                for (int k = 0; k < 8; ++k) s = fmaf(v8[k], W1[k * H1 + j], s);
                s = fmaxf(s, 0.f);
                const unsigned short hb = f2bf(s);
                const int off = frag_off(j, m);
                a1h[off] = hb;
                a1l[off] = f2bf(s - bfu2f(hb));
            }
        }
        __syncthreads();

        // ---- P1: z,r pre-activations, single accumulator per chunk-iter ----
        for (int it = wv; it < 2 * NCH; it += 4) {
            const int g = it / NCH;        // 0=z, 1=r
            const int c = it - g * NCH;
            f32x4 acc = zero4;
            const unsigned short* fx = WF + (size_t)((g * NCH + c) * SL_X) * 512 + laneo;
            for (int s = 0; s < SL_X; ++s) {
                const short8 Ahi = *(const short8*)(a1h + s * 512 + laneo);
                const short8 Alo = *(const short8*)(a1l + s * 512 + laneo);
                const short8 B  = *(const short8*)(fx + s * 512);
                acc = MFMA(Alo, B, acc);
                acc = MFMA(Ahi, B, acc);
            }
            const unsigned short* fh = UgF + (size_t)((g * NCH + c) * SL_H) * 512 + laneo;
            for (int s = 0; s < SL_H; ++s) {
                const short8 Ahi = *(const short8*)(hh_ + s * 512 + laneo);
                const short8 Alo = *(const short8*)(hl_ + s * 512 + laneo);
                const short8 B  = *(const short8*)(fh + s * 512);
                acc = MFMA(Alo, B, acc);
                acc = MFMA(Ahi, B, acc);
            }
            const int n  = 16 * c + (lane & 15);
            const float b = g ? s_br[n] : s_bz[n];
#pragma unroll
            for (int i = 0; i < 4; ++i)
                s_zr[g][(lane >> 4) * 4 + i][n] = sigmoid_(acc[i] + b);
        }
        __syncthreads();

        // ---- P2: hcand chunks; stash h_new in regs across the barrier ----
        f32x4 hstash[4];
#pragma unroll
        for (int q = 0; q < 4; ++q) {
            hstash[q] = zero4;
            const int c = wv + 4 * q;
            if (c < NCH) {
                f32x4 ax = zero4, ah4 = zero4;
                const unsigned short* fx = WF + (size_t)((2 * NCH + c) * SL_X) * 512 + laneo;
                for (int s = 0; s < SL_X; ++s) {
                    const short8 Ahi = *(const short8*)(a1h + s * 512 + laneo);
                    const short8 Alo = *(const short8*)(a1l + s * 512 + laneo);
                    const short8 B  = *(const short8*)(fx + s * 512);
                    ax = MFMA(Alo, B, ax);
                    ax = MFMA(Ahi, B, ax);
                }
                const unsigned short* fh = UgF + (size_t)((2 * NCH + c) * SL_H) * 512 + laneo;
                for (int s = 0; s < SL_H; ++s) {
                    const short8 Ahi = *(const short8*)(hh_ + s * 512 + laneo);
                    const short8 Alo = *(const short8*)(hl_ + s * 512 + laneo);
                    const short8 B  = *(const short8*)(fh + s * 512);
                    ah4 = MFMA(Alo, B, ah4);
                    ah4 = MFMA(Ahi, B, ah4);
                }
                const int n  = 16 * c + (lane & 15);
                const float bx = s_bhx[n], bh = s_bhh[n];
#pragma unroll
                for (int i = 0; i < 4; ++i) {
                    const int m   = (lane >> 4) * 4 + i;
                    const float z  = s_zr[0][m][n];
                    const float rr = s_zr[1][m][n];
                    const int off = frag_off(n, m);
                    const float hold = bfu2f(hh_[off]) + bfu2f(hl_[off]);
                    const float hc = tanh_((ax[i] + bx) + rr * (ah4[i] + bh));
                    hstash[q][i] = z * hold + (1.f - z) * hc;
                }
            }
        }
        __syncthreads();  // all reads of old h complete

#pragma unroll
        for (int q = 0; q < 4; ++q) {
            const int c = wv + 4 * q;
            if (c < NCH) {
                const int n = 16 * c + (lane & 15);
                if (n < 200) {
#pragma unroll
                    for (int i = 0; i < 4; ++i) {
                        const int m   = (lane >> 4) * 4 + i;
                        const int off = frag_off(n, m);
                        const float hn = hstash[q][i];
                        const unsigned short hb = f2bf(hn);
                        hh_[off] = hb;
                        hl_[off] = f2bf(hn - bfu2f(hb));
                    }
                }
            }
        }
        __syncthreads();  // new h visible (K-pad rows stay zero)

        // ---- P3: a2 = relu(h @ W2); 5 N-tiles per wave, 1 acc each ----
#pragma unroll
        for (int q = 0; q < 5; ++q) {
            const int tl = wv + 4 * q;  // 0..19
            f32x4 acc = zero4;
            const unsigned short* fb = W2F + (size_t)(tl * SL_H) * 512 + laneo;
            for (int s = 0; s < SL_H; ++s) {
                const short8 Ahi = *(const short8*)(hh_ + s * 512 + laneo);
                const short8 Alo = *(const short8*)(hl_ + s * 512 + laneo);
                const short8 B  = *(const short8*)(fb + s * 512);
                acc = MFMA(Alo, B, acc);
                acc = MFMA(Ahi, B, acc);
            }
            const int n  = 16 * tl + (lane & 15);
            const float bb = s_b2[n];
            f32x4 o;
#pragma unroll
            for (int i = 0; i < 4; ++i) o[i] = fmaxf(acc[i] + bb, 0.f);
            *(f32x4*)(s_a2 + n * 16 + (lane >> 4) * 4) = o;  // overwrites s_zr (dead)
        }
        __syncthreads();

        // ---- Phase E: KG = a2 @ W3 + b3 (VALU, 128 threads) ----
        if (tid < 128) {
            const int r = tid >> 3, c = tid & 7;
            float acc = b3[c];
            for (int k = 0; k < H2; ++k) acc = fmaf(s_a2[k * 16 + r], W3[k * 8 + c], acc);
            s_kg[r][c] = acc;
        }
        __syncthreads();

        // ---- Phase F: posterior update + output ----
        if (tid < 16) {
            const int r = tid;
            const float d0 = s_dm1y[r][0], d1 = s_dm1y[r][1];
            float p[4];
#pragma unroll
            for (int m = 0; m < 4; ++m) {
                p[m] = s_prior[r][m] + s_kg[r][2 * m] * d0 + s_kg[r][2 * m + 1] * d1;
                s_post[r][m] = p[m];
            }
            *reinterpret_cast<float4*>(&out[((size_t)t * BATCH + row0 + r) * 4]) =
                *reinterpret_cast<const float4*>(p);
        }
        __syncthreads();
    }
}

// ================= scalar fp32 fallback (R2-verified structure) =================
constexpr int FBR = 8;
__device__ __forceinline__ void load8f(const float* __restrict__ p, float* a) {
    const float4* v = reinterpret_cast<const float4*>(p);
    const float4 t0 = v[0], t1 = v[1];
    a[0] = t0.x; a[1] = t0.y; a[2] = t0.z; a[3] = t0.w;
    a[4] = t1.x; a[5] = t1.y; a[6] = t1.z; a[7] = t1.w;
}
__global__ __launch_bounds__(256, 4) void knet_fb(
    const float* __restrict__ y, const float* __restrict__ Fm, const float* __restrict__ Hm,
    const float* __restrict__ W1, const float* __restrict__ b1, const float* __restrict__ Wg,
    const float* __restrict__ Ug, const float* __restrict__ bg, const float* __restrict__ W2,
    const float* __restrict__ b2, const float* __restrict__ W3, const float* __restrict__ b3,
    const float* __restrict__ hn0, float* __restrict__ out) {
    __shared__ float s_hnt[HID][FBR];
    __shared__ float s_act[H1][FBR];
    __shared__ float s_in8[FBR][9], s_dm1y[FBR][2], s_prior[FBR][4], s_post[FBR][4], s_kg[FBR][8];
    const int tid = threadIdx.x;
    const int row0 = blockIdx.x * FBR;
    for (int idx = tid; idx < FBR * HID; idx += 256) {
        const int r = idx / HID, k = idx - r * HID;
        s_hnt[k][r] = hn0[(size_t)(row0 + r) * HID + k];
    }
    if (tid < FBR * 4) { s_prior[tid >> 2][tid & 3] = 0.f; s_post[tid >> 2][tid & 3] = 0.f; }
    __syncthreads();
    for (int t = 0; t < T_STEPS; ++t) {
        if (tid < FBR) {
            const int r = tid;
            float post[4], prevpri[4], pri[4];
            for (int m = 0; m < 4; ++m) { post[m] = s_post[r][m]; prevpri[m] = s_prior[r][m]; }
            for (int m = 0; m < 4; ++m) {
                float s = 0.f;
                for (int j = 0; j < 4; ++j) s += Fm[m * 4 + j] * post[j];
                pri[m] = s;
            }
            float dy[2];
            for (int n = 0; n < 2; ++n) {
                float s = 0.f;
                for (int m = 0; m < 4; ++m) s += Hm[n * 4 + m] * pri[m];
                dy[n] = y[((size_t)t * BATCH + row0 + r) * 2 + n] - s;
            }
            float dx[4], ssx = 0.f;
            for (int m = 0; m < 4; ++m) { dx[m] = post[m] - prevpri[m]; ssx += dx[m] * dx[m]; }
            const float idx_ = rsqrtf(fmaxf(ssx, 1e-12f));
            const float idy_ = rsqrtf(fmaxf(dy[0] * dy[0] + dy[1] * dy[1], 1e-12f));
            s_in8[r][0] = dy[0] * idy_; s_in8[r][1] = dy[1] * idy_;
            s_in8[r][2] = dy[0] * idy_; s_in8[r][3] = dy[1] * idy_;
            for (int m = 0; m < 4; ++m) s_in8[r][4 + m] = dx[m] * idx_;
            s_dm1y[r][0] = dy[0]; s_dm1y[r][1] = dy[1];
            for (int m = 0; m < 4; ++m) s_prior[r][m] = pri[m];
        }
        __syncthreads();
        {
            const int r = tid & (FBR - 1);
            float v[8];
            for (int k = 0; k < 8; ++k) v[k] = s_in8[r][k];
            for (int j = tid >> 3; j < H1; j += 32) {
                float s = b1[j];
                for (int k = 0; k < 8; ++k) s = fmaf(v[k], W1[k * H1 + j], s);
                s_act[j][r] = fmaxf(s, 0.f);
            }
        }
        __syncthreads();
        float hnew[FBR];
        if (tid < HID) {
            const int j = tid;
            float az[FBR], arr[FBR], ahx[FBR], ahh[FBR];
            for (int r = 0; r < FBR; ++r) { az[r] = arr[r] = ahx[r] = ahh[r] = 0.f; }
            for (int k = 0; k < H1; ++k) {
                const float wz = Wg[k * 600 + j], wr = Wg[k * 600 + j + HID], wh = Wg[k * 600 + j + 2 * HID];
                float a[FBR];
                load8f(&s_act[k][0], a);
                for (int r = 0; r < FBR; ++r) {
                    az[r] = fmaf(a[r], wz, az[r]); arr[r] = fmaf(a[r], wr, arr[r]); ahx[r] = fmaf(a[r], wh, ahx[r]);
                }
            }
            for (int k = 0; k < HID; ++k) {
                const float uz = Ug[k * 600 + j], ur = Ug[k * 600 + j + HID], uh = Ug[k * 600 + j + 2 * HID];
                float h[FBR];
                load8f(&s_hnt[k][0], h);
                for (int r = 0; r < FBR; ++r) {
                    az[r] = fmaf(h[r], uz, az[r]); arr[r] = fmaf(h[r], ur, arr[r]); ahh[r] = fmaf(h[r], uh, ahh[r]);
                }
            }
            const float bz = bg[j] + bg[600 + j], brr = bg[HID + j] + bg[600 + HID + j];
            const float bhx = bg[2 * HID + j], bhh = bg[600 + 2 * HID + j];
            float ho[FBR];
            load8f(&s_hnt[j][0], ho);
            for (int r = 0; r < FBR; ++r) {
                const float z = sigmoid_(az[r] + bz), rr = sigmoid_(arr[r] + brr);
                const float hc = tanh_((ahx[r] + bhx) + rr * (ahh[r] + bhh));
                hnew[r] = z * ho[r] + (1.f - z) * hc;
            }
        }
        __syncthreads();
        if (tid < HID) {
            float4* dst = reinterpret_cast<float4*>(&s_hnt[tid][0]);
            const float4* src = reinterpret_cast<const float4*>(hnew);
            dst[0] = src[0]; dst[1] = src[1];
        }
        __syncthreads();
        for (int j = tid; j < H2; j += 256) {
            float acc[FBR];
            for (int r = 0; r < FBR; ++r) acc[r] = 0.f;
            for (int k = 0; k < HID; ++k) {
                const float w = W2[k * H2 + j];
                float h[FBR];
                load8f(&s_hnt[k][0], h);
                for (int r = 0; r < FBR; ++r) acc[r] = fmaf(h[r], w, acc[r]);
            }
            for (int r = 0; r < FBR; ++r) s_act[j][r] = fmaxf(acc[r] + b2[j], 0.f);
        }
        __syncthreads();
        if (tid < FBR * 8) {
            const int r = tid >> 3, c = tid & 7;
            float acc = b3[c];
            for (int k = 0; k < H2; ++k) acc = fmaf(s_act[k][r], W3[k * 8 + c], acc);
            s_kg[r][c] = acc;
        }
        __syncthreads();
        if (tid < FBR) {
            const int r = tid;
            const float d0 = s_dm1y[r][0], d1 = s_dm1y[r][1];
            float p[4];
            for (int m = 0; m < 4; ++m) {
                p[m] = s_prior[r][m] + s_kg[r][2 * m] * d0 + s_kg[r][2 * m + 1] * d1;
                s_post[r][m] = p[m];
            }
            *reinterpret_cast<float4*>(&out[((size_t)t * BATCH + row0 + r) * 4]) =
                *reinterpret_cast<const float4*>(p);
        }
        __syncthreads();
    }
}

}  // namespace

extern "C" void kernel_launch(void* const* d_in, const int* in_sizes, int n_in,
                              void* d_out, int out_size, void* d_ws, size_t ws_size,
                              hipStream_t stream) {
    const float* y   = (const float*)d_in[0];
    const float* Fm  = (const float*)d_in[1];
    const float* Hm  = (const float*)d_in[2];
    const float* W1  = (const float*)d_in[3];
    const float* b1  = (const float*)d_in[4];
    const float* Wg  = (const float*)d_in[5];
    const float* Ug  = (const float*)d_in[6];
    const float* bg  = (const float*)d_in[7];
    const float* W2  = (const float*)d_in[8];
    const float* b2  = (const float*)d_in[9];
    const float* W3  = (const float*)d_in[10];
    const float* b3  = (const float*)d_in[11];
    const float* hn0 = (const float*)d_in[12];
    float* out = (float*)d_out;

    if (ws_size >= WS_NEED) {
        unsigned short* WFr = (unsigned short*)d_ws;
        cvt_kernel<<<(FRAGS * 512 + 255) / 256, 256, 0, stream>>>(Wg, Ug, W2, WFr);
        knet_mfma<<<dim3(BATCH / BR), dim3(NTHR), 0, stream>>>(
            y, Fm, Hm, W1, b1, bg, b2, W3, b3, hn0, WFr, out);
    } else {
        knet_fb<<<dim3(BATCH / FBR), dim3(256), 0, stream>>>(
            y, Fm, Hm, W1, b1, Wg, Ug, bg, W2, b2, W3, b3, hn0, out);
    }
}